// Round 5
// baseline (311.713 us; speedup 1.0000x reference)
//
#include <hip/hip_runtime.h>

typedef unsigned short u16;
typedef _Float16 h8 __attribute__((ext_vector_type(8)));
typedef __fp16 fp16x2 __attribute__((ext_vector_type(2)));
typedef float f32x4 __attribute__((ext_vector_type(4)));

constexpr int B_ = 4, S_ = 2048, D_ = 1024, H_ = 16;

// async global->LDS, 16B per lane; LDS dest = (wave-uniform base) + lane*16
__device__ __forceinline__ void async16(const void* g, void* l) {
  __builtin_amdgcn_global_load_lds(
      (const __attribute__((address_space(1))) void*)g,
      (__attribute__((address_space(3))) void*)l, 16, 0, 0);
}

// pack two f32 -> fp16x2 (RTZ) as a raw uint
__device__ __forceinline__ unsigned pk2(float a, float b) {
  union { fp16x2 h; unsigned u; } c;
  c.h = __builtin_amdgcn_cvt_pkrtz(a, b);
  return c.u;
}

// raw hardware exp2 (v_exp_f32), no ln2 multiply
__device__ __forceinline__ float fexp2(float x) {
#if __has_builtin(__builtin_amdgcn_exp2f)
  return __builtin_amdgcn_exp2f(x);
#else
  return exp2f(x);
#endif
}

// log2(e)/8: folded into the Q columns of the QKV GEMM epilogue (f32, before
// the single fp16 rounding -> same error structure as the exact-1/8 path).
#define QSCALE 0.18033688011112042f

// ---------------------------------------------------------------------------
// fp32 -> fp16 convert for all three tensors in ONE launch.
// Region split by blockIdx: x [0,8192), wi [8192,11264), wo [11264,12288).
// ---------------------------------------------------------------------------
__global__ __launch_bounds__(256) void cvt3_kernel(
    const float* __restrict__ x, const float* __restrict__ wi,
    const float* __restrict__ wo, _Float16* __restrict__ xh,
    _Float16* __restrict__ wih, _Float16* __restrict__ woh)
{
  const int bid = blockIdx.x;
  const float* src;
  _Float16* dst;
  int base;
  if (bid < 8192)       { src = x;  dst = xh;  base = bid; }
  else if (bid < 11264) { src = wi; dst = wih; base = bid - 8192; }
  else                  { src = wo; dst = woh; base = bid - 11264; }
  const int i = (base * 256 + threadIdx.x) * 4;
  const float4 v = *(const float4*)(src + i);
  uint2 o;
  o.x = pk2(v.x, v.y);
  o.y = pk2(v.z, v.w);
  *(uint2*)(dst + i) = o;
}

// ---------------------------------------------------------------------------
// 256xBN deep-pipelined GEMM, BN = BPW*64.  C = A Bw^T + bias.
// 512 threads = 8 waves (2m x 4n), wave tile 128 x (BN/4), acc[8][BPW].
// Frag-major LDS (zero bank conflicts, staging order == fragment order).
// WRITE-BEHIND pipeline, prefetch distance 2, NO mid-loop vmcnt(0); boundary
// wait = counted vmcnt(4+BPW) retiring exactly the next tile's loads (issued
// a full tile earlier). 5 barriers per K-tile.
// SCALE_Q (QKV only): Q columns (col<1024) scaled by log2(e)/8 in f32 before
// the fp16 store, so attention can use raw v_exp_f32.
// ---------------------------------------------------------------------------
template<bool OUT_HALF, int BPW, bool SCALE_Q>
__global__ __launch_bounds__(512, 2) void gemm256d_f16(
    const _Float16* __restrict__ A, const _Float16* __restrict__ Bw,
    const float* __restrict__ bias, void* __restrict__ Cout,
    int M, int N, int K)
{
  constexpr int BN = BPW * 64;
  constexpr int NBB = BN / 8;  // B frag-blocks per K-tile
  __shared__ __align__(16) _Float16 sA[2][16384];
  __shared__ __align__(16) _Float16 sB[2][NBB * 512];

  const int tid = threadIdx.x;
  const int lane = tid & 63, w = tid >> 6;   // 8 waves
  const int wm = w >> 2, wn = w & 3;         // 2 x 4 wave grid

  // XCD-bijective swizzle (gridDim.x % 8 == 0)
  const int id = blockIdx.x;
  const int cpx = gridDim.x >> 3;
  const int swz = (id & 7) * cpx + (id >> 3);
  const int nbx = N / BN;
  const int bx = swz % nbx, by = swz / nbx;
  const int m0 = by * 256, n0 = bx * BN;

  // Staging map: wave w owns A m-tiles {2w,2w+1} (4 loads) and B
  // frag-blocks {w*BPW .. w*BPW+BPW-1} (BPW loads).
  const int r15 = lane & 15, s4 = lane >> 4;
  const _Float16* gA[4];
  int loA[4];
#pragma unroll
  for (int j = 0; j < 4; ++j) {
    const int t = 2 * w + (j >> 1), kk = j & 1;
    gA[j] = A + (size_t)(m0 + 16 * t + r15) * K + kk * 32 + s4 * 8;
    loA[j] = (t * 2 + kk) * 512;
  }
  const _Float16* gB[BPW];
  int loB[BPW];
#pragma unroll
  for (int j = 0; j < BPW; ++j) {
    const int f = w * BPW + j, nt = f >> 1, kk = f & 1;
    gB[j] = Bw + (size_t)(n0 + 16 * nt + r15) * K + kk * 32 + s4 * 8;
    loB[j] = f * 512;
  }

  const f32x4 zf = {0.f, 0.f, 0.f, 0.f};
  f32x4 acc[8][BPW];
#pragma unroll
  for (int i = 0; i < 8; ++i)
#pragma unroll
    for (int j = 0; j < BPW; ++j) acc[i][j] = zf;

  // prologue: tiles 0 and 1 fully staged; retire tile 0's (4+BPW) loads
#pragma unroll
  for (int j = 0; j < 4; ++j) async16(gA[j], &sA[0][loA[j]]);
#pragma unroll
  for (int j = 0; j < BPW; ++j) async16(gB[j], &sB[0][loB[j]]);
#pragma unroll
  for (int j = 0; j < 4; ++j) async16(gA[j] + 64, &sA[1][loA[j]]);
#pragma unroll
  for (int j = 0; j < BPW; ++j) async16(gB[j] + 64, &sB[1][loB[j]]);
  if constexpr (BPW == 2)      asm volatile("s_waitcnt vmcnt(6)" ::: "memory");
  else if constexpr (BPW == 3) asm volatile("s_waitcnt vmcnt(7)" ::: "memory");
  else                         asm volatile("s_waitcnt vmcnt(8)" ::: "memory");
  __builtin_amdgcn_s_barrier();

  const int NT = K >> 6;
  int cur = 0;
  for (int kt = 0; kt < NT; ++kt) {
    const _Float16* pA = sA[cur];
    const _Float16* pB = sB[cur];
    _Float16* nA = sA[cur];  // write-behind: stage tile kt+2 into read buffer
    _Float16* nB = sB[cur];
    const bool st = (kt + 2 < NT);
    const int ko = (kt + 2) * 64;

    h8 fb[BPW][2];
#pragma unroll
    for (int p = 0; p < 4; ++p) {
      if (p == 0) {
#pragma unroll
        for (int nt = 0; nt < BPW; ++nt)
#pragma unroll
          for (int kk = 0; kk < 2; ++kk)
            fb[nt][kk] = *(const h8*)&pB[((wn * BPW + nt) * 2 + kk) * 512 + lane * 8];
      } else if (st) {
        if (p == 1) {
#pragma unroll
          for (int j = 0; j < BPW; ++j) async16(gB[j] + ko, &nB[loB[j]]);
        }
        if ((w & 3) == p - 1) {
#pragma unroll
          for (int j = 0; j < 4; ++j) async16(gA[j] + ko, &nA[loA[j]]);
        }
      }
      h8 fa[2][2];
#pragma unroll
      for (int i = 0; i < 2; ++i)
#pragma unroll
        for (int kk = 0; kk < 2; ++kk)
          fa[i][kk] = *(const h8*)&pA[((wm * 8 + 2 * p + i) * 2 + kk) * 512 + lane * 8];
      __builtin_amdgcn_s_setprio(1);
#pragma unroll
      for (int i = 0; i < 2; ++i)
#pragma unroll
        for (int nt = 0; nt < BPW; ++nt)
#pragma unroll
          for (int kk = 0; kk < 2; ++kk)
            acc[2 * p + i][nt] = __builtin_amdgcn_mfma_f32_16x16x32_f16(
                fa[i][kk], fb[nt][kk], acc[2 * p + i][nt], 0, 0, 0);
      __builtin_amdgcn_s_setprio(0);
      __builtin_amdgcn_s_barrier();  // phase-p closing barrier (staging license)
    }
    // waves with (w&3)==3: their A m-tiles freed only after phase 3
    if (st && (w & 3) == 3) {
#pragma unroll
      for (int j = 0; j < 4; ++j) async16(gA[j] + ko, &nA[loA[j]]);
    }
    if (kt + 1 < NT) {
      if (st) {  // retire tile kt+1's loads; tile kt+2's stay in flight
        if constexpr (BPW == 2)      asm volatile("s_waitcnt vmcnt(6)" ::: "memory");
        else if constexpr (BPW == 3) asm volatile("s_waitcnt vmcnt(7)" ::: "memory");
        else                         asm volatile("s_waitcnt vmcnt(8)" ::: "memory");
      } else {
        asm volatile("s_waitcnt vmcnt(0)" ::: "memory");
      }
      __builtin_amdgcn_s_barrier();  // boundary: all waves' next tile landed
    }
    cur ^= 1;
  }

  // ---- epilogue
  const int g = lane >> 4, cc = lane & 15;
#pragma unroll
  for (int nt = 0; nt < BPW; ++nt) {
    const int col = n0 + wn * (16 * BPW) + nt * 16 + cc;
    const float bv = bias[col];
    float qs = 1.0f;
    if constexpr (SCALE_Q) qs = (col < 1024) ? QSCALE : 1.0f;
#pragma unroll
    for (int mt = 0; mt < 8; ++mt) {
      const int rowb = m0 + wm * 128 + mt * 16 + g * 4;
#pragma unroll
      for (int r = 0; r < 4; ++r) {
        float v = acc[mt][nt][r] + bv;
        if constexpr (SCALE_Q) v *= qs;
        if constexpr (OUT_HALF)
          ((_Float16*)Cout)[(size_t)(rowb + r) * N + col] = (_Float16)v;
        else
          ((float*)Cout)[(size_t)(rowb + r) * N + col] = v;
      }
    }
  }
}

// ---------------------------------------------------------------------------
// V transpose: qkv fp16 [B,S,3D] (V at col 2048+h*64+d) -> vT [(b,h,d)][S]
// ---------------------------------------------------------------------------
__global__ __launch_bounds__(256) void transpose_v(
    const u16* __restrict__ qkv, u16* __restrict__ vT)
{
  __shared__ u16 T[64 * 73];
  const int tid = threadIdx.x;
  const int bh = blockIdx.y, s0 = blockIdx.x * 64;
  const int b = bh >> 4, h = bh & 15;
#pragma unroll
  for (int t = 0; t < 2; ++t) {
    const int c = tid + t * 256, r = c >> 3, cs = c & 7;
    union { int4 v; u16 s[8]; } u;
    u.v = *(const int4*)(qkv + (size_t)(b * S_ + s0 + r) * 3072 + 2048 + h * 64 + 8 * cs);
#pragma unroll
    for (int i = 0; i < 8; ++i) T[r * 73 + 8 * cs + i] = u.s[i];
  }
  __syncthreads();
#pragma unroll
  for (int t = 0; t < 2; ++t) {
    const int c = tid + t * 256, rd = c >> 3, ss = c & 7;
    union { int4 v; u16 s[8]; } u;
#pragma unroll
    for (int i = 0; i < 8; ++i) u.s[i] = T[(8 * ss + i) * 73 + rd];
    *(int4*)(vT + (size_t)(bh * 64 + rd) * S_ + s0 + 8 * ss) = u.v;
  }
}

// ---------------------------------------------------------------------------
// Flash attention fp16. Block = 128 q-rows of one (b,h), 4 waves, wave owns
// 32 q (m=2 tiles). S^T via mfma(kf,qf); sP aliases sQ. K/V/Q staged with
// global_load_lds width 16. LDS 34 KiB -> 4 blocks/CU.
// Q arrives PRE-SCALED by log2(e)/8 (GEMM epilogue) -> P = exp2(S) with raw
// v_exp_f32, no per-score multiply (VALU was the bottleneck: 43% vs 35% MFMA).
// setprio(1) around MFMA clusters (T5: blocks are phase-decoupled).
// ---------------------------------------------------------------------------
__global__ __launch_bounds__(256, 4) void attn_f16(
    const _Float16* __restrict__ qkv, const _Float16* __restrict__ vT,
    _Float16* __restrict__ attnO, const int* __restrict__ causal_ptr)
{
  __shared__ __align__(16) _Float16 sQP[9216];  // Q staging, then P (4w x 32 x 72)
  __shared__ __align__(16) _Float16 sK[4096];
  __shared__ __align__(16) _Float16 sV[4096];

  const int tid = threadIdx.x, lane = tid & 63, w = tid >> 6;
  const int q4 = lane >> 4, cc = lane & 15;
  const int bh = blockIdx.y, b = bh >> 4, h = bh & 15;
  const int q0 = blockIdx.x * 128;
  const int causal = causal_ptr[0];

  {
    const int rr = lane & 15, sc8 = lane >> 4;
#pragma unroll
    for (int tt = 0; tt < 2; ++tt) {
      const int t = 2 * w + tt;
#pragma unroll
      for (int sh = 0; sh < 2; ++sh) {
        const _Float16* g = qkv + (size_t)(b * S_ + q0 + 16 * t + rr) * 3072 + h * 64 + 8 * (4 * sh + sc8);
        async16(g, &sQP[t * 1024 + sh * 512]);
      }
    }
  }
  __syncthreads();  // Q landed

  // Q frags (already carry the log2(e)/8 score scale from the GEMM epilogue)
  h8 qf[2][2];
#pragma unroll
  for (int m = 0; m < 2; ++m)
#pragma unroll
    for (int kk = 0; kk < 2; ++kk)
      qf[m][kk] = *(const h8*)&sQP[((2 * w + m) << 10) + (kk << 9) + (lane << 3)];

  h8 ones;
#pragma unroll
  for (int i = 0; i < 8; ++i) ones[i] = (_Float16)1.0f;

  const _Float16* gK = qkv + (size_t)(b * S_ + 16 * w + (lane & 15)) * 3072 + 1024 + h * 64 + 8 * (lane >> 4);
  const _Float16* gV = vT + (size_t)(bh * 64 + 16 * w + (lane & 15)) * S_ + 8 * (lane >> 4);
  _Float16* lK0 = &sK[w * 1024];
  _Float16* lV0 = &sV[w * 1024];

  const int wp = w * 2304;

  const f32x4 zf = {0.f, 0.f, 0.f, 0.f};
  f32x4 oa[2][4], lac[2];
#pragma unroll
  for (int m = 0; m < 2; ++m) {
    lac[m] = zf;
#pragma unroll
    for (int nt = 0; nt < 4; ++nt) oa[m][nt] = zf;
  }

  for (int j0 = 0; j0 < S_; j0 += 64) {
    if (causal && j0 > q0 + 127) break;
    __syncthreads();
    async16(gK + (size_t)j0 * 3072, lK0);
    async16(gK + (size_t)j0 * 3072 + 32, lK0 + 512);
    async16(gV + j0, lV0);
    async16(gV + j0 + 32, lV0 + 512);
    __syncthreads();

    f32x4 sc[2][4];
    __builtin_amdgcn_s_setprio(1);
#pragma unroll
    for (int nt = 0; nt < 4; ++nt) {
      const h8 kf0 = *(const h8*)&sK[(nt << 10) + (lane << 3)];
      const h8 kf1 = *(const h8*)&sK[(nt << 10) + 512 + (lane << 3)];
#pragma unroll
      for (int m = 0; m < 2; ++m) {
        sc[m][nt] = __builtin_amdgcn_mfma_f32_16x16x32_f16(kf0, qf[m][0], zf, 0, 0, 0);
        sc[m][nt] = __builtin_amdgcn_mfma_f32_16x16x32_f16(kf1, qf[m][1], sc[m][nt], 0, 0, 0);
      }
    }
    __builtin_amdgcn_s_setprio(0);

    if (causal) {
#pragma unroll
      for (int m = 0; m < 2; ++m)
#pragma unroll
        for (int nt = 0; nt < 4; ++nt)
#pragma unroll
          for (int r = 0; r < 4; ++r)
            if ((j0 + nt * 16 + q4 * 4 + r) > (q0 + 32 * w + m * 16 + cc))
              sc[m][nt][r] = -1.0e30f;
    }

    // P = exp2(S): scores arrive in log2 units; raw v_exp_f32, no multiply
#pragma unroll
    for (int m = 0; m < 2; ++m)
#pragma unroll
      for (int nt = 0; nt < 4; ++nt) {
        uint2 pk;
        pk.x = pk2(fexp2(sc[m][nt][0]), fexp2(sc[m][nt][1]));
        pk.y = pk2(fexp2(sc[m][nt][2]), fexp2(sc[m][nt][3]));
        *(uint2*)&sQP[wp + (m * 16 + cc) * 72 + nt * 16 + q4 * 4] = pk;
      }

    asm volatile("s_waitcnt lgkmcnt(0)" ::: "memory");

    h8 pf[2][2];
#pragma unroll
    for (int m = 0; m < 2; ++m)
#pragma unroll
      for (int kk = 0; kk < 2; ++kk)
        pf[m][kk] = *(const h8*)&sQP[wp + (m * 16 + cc) * 72 + kk * 32 + q4 * 8];

    __builtin_amdgcn_s_setprio(1);
#pragma unroll
    for (int m = 0; m < 2; ++m) {
      lac[m] = __builtin_amdgcn_mfma_f32_16x16x32_f16(pf[m][0], ones, lac[m], 0, 0, 0);
      lac[m] = __builtin_amdgcn_mfma_f32_16x16x32_f16(pf[m][1], ones, lac[m], 0, 0, 0);
    }
#pragma unroll
    for (int nt = 0; nt < 4; ++nt) {
      const h8 vf0 = *(const h8*)&sV[(nt << 10) + (lane << 3)];
      const h8 vf1 = *(const h8*)&sV[(nt << 10) + 512 + (lane << 3)];
#pragma unroll
      for (int m = 0; m < 2; ++m) {
        oa[m][nt] = __builtin_amdgcn_mfma_f32_16x16x32_f16(pf[m][0], vf0, oa[m][nt], 0, 0, 0);
        oa[m][nt] = __builtin_amdgcn_mfma_f32_16x16x32_f16(pf[m][1], vf1, oa[m][nt], 0, 0, 0);
      }
    }
    __builtin_amdgcn_s_setprio(0);
  }

#pragma unroll
  for (int m = 0; m < 2; ++m) {
    float inv[4];
#pragma unroll
    for (int r = 0; r < 4; ++r) inv[r] = 1.0f / lac[m][r];
#pragma unroll
    for (int nt = 0; nt < 4; ++nt) {
      const int col = h * 64 + nt * 16 + cc;
#pragma unroll
      for (int r = 0; r < 4; ++r) {
        const int row = b * S_ + q0 + 32 * w + m * 16 + q4 * 4 + r;
        attnO[(size_t)row * D_ + col] = (_Float16)(oa[m][nt][r] * inv[r]);
      }
    }
  }
}

// ---------------------------------------------------------------------------
extern "C" void kernel_launch(void* const* d_in, const int* in_sizes, int n_in,
                              void* d_out, int out_size, void* d_ws, size_t ws_size,
                              hipStream_t stream)
{
  const float* x  = (const float*)d_in[0];
  const float* wi = (const float*)d_in[1];
  const float* bi = (const float*)d_in[2];
  const float* wo = (const float*)d_in[3];
  const float* bo = (const float*)d_in[4];
  const int* causal = (const int*)d_in[5];

  _Float16* xh   = (_Float16*)d_ws;       // 8192*1024
  _Float16* wih  = xh + 8388608;          // 3072*1024
  _Float16* woh  = wih + 3145728;         // 1024*1024
  _Float16* qkvb = woh + 1048576;         // 8192*3072
  _Float16* vT   = qkvb + 25165824;       // 4096*2048
  _Float16* attn = vT + 8388608;          // 8192*1024

  const int M = B_ * S_;  // 8192

  cvt3_kernel<<<12288, 256, 0, stream>>>(x, wi, wo, xh, wih, woh);

  // QKV projection: BN=192 -> 32*16 = 512 blocks = exactly 2 full rounds.
  // Q columns pre-scaled by log2(e)/8 for exp2-based softmax.
  gemm256d_f16<true, 3, true><<<512, 512, 0, stream>>>(
      xh, wih, bi, qkvb, M, 3 * D_, D_);

  transpose_v<<<dim3(32, 64), 256, 0, stream>>>((const u16*)qkvb, (u16*)vT);

  attn_f16<<<dim3(16, 64), 256, 0, stream>>>(qkvb, vT, attn, causal);

  // out-proj: BN=128 -> 32*8 = 256 blocks = exactly 1 full round, 1 block/CU.
  gemm256d_f16<false, 2, false><<<256, 512, 0, stream>>>(
      attn, woh, bo, d_out, M, D_, D_);
}